// Round 1
// baseline (6834.882 us; speedup 1.0000x reference)
//
#include <hip/hip_runtime.h>

#define S_LEN 8192
#define NH 16
#define NV 4
#define NB 512

__device__ __forceinline__ float bperm(int byteIdx, float v) {
    return __int_as_float(__builtin_amdgcn_ds_bpermute(byteIdx, __float_as_int(v)));
}
__device__ __forceinline__ float fsig(float x) {
    // sigmoid(x) = 1/(1+e^-x)
    return __builtin_amdgcn_rcpf(1.0f + __expf(-x));
}
__device__ __forceinline__ float ftanh(float x) {
    // tanh(x) = 2/(1+e^-2x) - 1
    return fmaf(2.0f, __builtin_amdgcn_rcpf(1.0f + __expf(-2.0f * x)), -1.0f);
}

// 128 blocks x 64 threads. Each wave: 4 batch elements x 16 lanes.
// Lane j (within its 16-lane group) owns hidden unit j of its batch element.
__global__ __launch_bounds__(64, 1) void rnn_kernel(
    const float* __restrict__ gt,
    const float* __restrict__ eWih, const float* __restrict__ eWhh,
    const float* __restrict__ ebih, const float* __restrict__ ebhh,
    const float* __restrict__ dWih, const float* __restrict__ dWhh,
    const float* __restrict__ dbih, const float* __restrict__ dbhh,
    const float* __restrict__ oW,  const float* __restrict__ ob,
    float* __restrict__ loss_out)
{
    const int lane = threadIdx.x;          // 0..63
    const int j    = lane & 15;            // hidden index
    const int q    = j & 3;                // out-gate this lane accumulates
    const int b    = blockIdx.x * 4 + (lane >> 4);
    const int gbb  = (lane & 48) << 2;     // byte base for ds_bpermute (group base lane * 4)

    const float* gb = gt + (size_t)b * (NV * S_LEN);   // gt[b, v, t] at gb[v*S_LEN + t]

    // ---------------- encoder weights (per lane) ----------------
    float ewr[NH], ewz[NH], ewn[NH];
#pragma unroll
    for (int k = 0; k < NH; ++k) {
        ewr[k] = eWhh[(0 * NH + j) * NH + k];
        ewz[k] = eWhh[(1 * NH + j) * NH + k];
        ewn[k] = eWhh[(2 * NH + j) * NH + k];
    }
    float exr[NV], exz[NV], exn[NV];
#pragma unroll
    for (int v = 0; v < NV; ++v) {
        exr[v] = eWih[(0 * NH + j) * NV + v];
        exz[v] = eWih[(1 * NH + j) * NV + v];
        exn[v] = eWih[(2 * NH + j) * NV + v];
    }
    const float c_er  = ebih[j] + ebhh[j];
    const float c_ez  = ebih[NH + j] + ebhh[NH + j];
    const float c_ein = ebih[2 * NH + j];
    const float c_ehn = ebhh[2 * NH + j];

    float h = 0.0f;

    // ---------------- encoder loop (prefetch x by 2 steps) ----------------
    float xa0 = gb[0 * S_LEN + 0], xa1 = gb[1 * S_LEN + 0], xa2 = gb[2 * S_LEN + 0], xa3 = gb[3 * S_LEN + 0];
    float xb0 = gb[0 * S_LEN + 1], xb1 = gb[1 * S_LEN + 1], xb2 = gb[2 * S_LEN + 1], xb3 = gb[3 * S_LEN + 1];

    auto estep = [&](float x0, float x1, float x2, float x3) {
        float ar = c_er, az = c_ez, hn = c_ehn;
#pragma unroll
        for (int i = 0; i < NH; ++i) {
            float hv = bperm(gbb + 4 * i, h);
            ar = fmaf(ewr[i], hv, ar);
            az = fmaf(ewz[i], hv, az);
            hn = fmaf(ewn[i], hv, hn);
        }
        ar = fmaf(exr[0], x0, ar); ar = fmaf(exr[1], x1, ar);
        ar = fmaf(exr[2], x2, ar); ar = fmaf(exr[3], x3, ar);
        az = fmaf(exz[0], x0, az); az = fmaf(exz[1], x1, az);
        az = fmaf(exz[2], x2, az); az = fmaf(exz[3], x3, az);
        float inn = c_ein;
        inn = fmaf(exn[0], x0, inn); inn = fmaf(exn[1], x1, inn);
        inn = fmaf(exn[2], x2, inn); inn = fmaf(exn[3], x3, inn);
        float r = fsig(ar), z = fsig(az);
        float n = ftanh(fmaf(r, hn, inn));
        h = fmaf(z, h - n, n);          // (1-z)*n + z*h
    };

    for (int t = 0; t < S_LEN; t += 2) {
        estep(xa0, xa1, xa2, xa3);
        int tn = t + 2; if (tn > S_LEN - 1) tn = S_LEN - 1;
        xa0 = gb[0 * S_LEN + tn]; xa1 = gb[1 * S_LEN + tn];
        xa2 = gb[2 * S_LEN + tn]; xa3 = gb[3 * S_LEN + tn];
        estep(xb0, xb1, xb2, xb3);
        int tm = t + 3; if (tm > S_LEN - 1) tm = S_LEN - 1;
        xb0 = gb[0 * S_LEN + tm]; xb1 = gb[1 * S_LEN + tm];
        xb2 = gb[2 * S_LEN + tm]; xb3 = gb[3 * S_LEN + tm];
    }

    // ---------------- decoder weights (loaded after encoder to limit live range) ----------------
    float dwr[NH], dwz[NH], dwn[NH], owp[NH];
#pragma unroll
    for (int k = 0; k < NH; ++k) {
        dwr[k] = dWhh[(0 * NH + j) * NH + k];
        dwz[k] = dWhh[(1 * NH + j) * NH + k];
        dwn[k] = dWhh[(2 * NH + j) * NH + k];
        owp[k] = oW[q * NH + k];
    }
    float Tr[NV], Tz[NV], Tn[NV];
#pragma unroll
    for (int c = 0; c < NV; ++c) {
        Tr[c] = dWih[(0 * NH + j) * NV + c];
        Tz[c] = dWih[(1 * NH + j) * NV + c];
        Tn[c] = dWih[(2 * NH + j) * NV + c];
    }
    const float c_dr  = dbih[j] + dbhh[j];
    const float c_dz  = dbih[NH + j] + dbhh[NH + j];
    const float c_din = dbih[2 * NH + j];
    const float c_dhn = dbhh[2 * NH + j];
    const float obq   = ob[q];

    float lloss = 0.0f;

    // target stream: iteration t (t>=1) consumes gt[t-1].
    // A holds even-index gt (used at odd t), B holds odd-index gt... see schedule below.
    float A0 = gb[0 * S_LEN + 0], A1 = gb[1 * S_LEN + 0], A2 = gb[2 * S_LEN + 0], A3 = gb[3 * S_LEN + 0]; // gt[0] -> t=1
    float B0 = gb[0 * S_LEN + 1], B1 = gb[1 * S_LEN + 1], B2 = gb[2 * S_LEN + 1], B3 = gb[3 * S_LEN + 1]; // gt[1] -> t=2

    // dstep: gathers current h (== h'(t-1)), accumulating both the GRU dots and the
    // output head for the PREVIOUS step; then finishes nll/argmax for step t-1,
    // selects the one-hot gi for step t, and updates h.
    auto dstep = [&](bool first, float p0, float p1, float p2, float p3) {
        float ar = c_dr, az = c_dz, hn = c_dhn, oa = obq;
#pragma unroll
        for (int i = 0; i < NH; ++i) {
            float hv = bperm(gbb + 4 * i, h);
            ar = fmaf(dwr[i], hv, ar);
            az = fmaf(dwz[i], hv, az);
            hn = fmaf(dwn[i], hv, hn);
            oa = fmaf(owp[i], hv, oa);   // full dot for out-gate q (lane sees all h)
        }
        float gr, gz, gn;
        if (first) {
            gr = gz = gn = 0.0f;         // x0 = zeros
        } else {
            // exchange the 4 out values within the 16-lane group
            float o_b = __shfl_xor(oa, 1, 64);   // out[q^1]
            float o_c = __shfl_xor(oa, 2, 64);   // out[q^2]
            float o_d = __shfl_xor(o_b, 2, 64);  // out[q^3]
            // ordered: out[i] lives in register m = i ^ q  (m: 0=oa,1=o_b,2=o_c,3=o_d)
            auto selo = [&](int m) {
                float lo = (m & 1) ? o_b : oa;
                float hi = (m & 1) ? o_d : o_c;
                return (m & 2) ? hi : lo;
            };
            float v0 = selo(q), v1 = selo(1 ^ q), v2 = selo(2 ^ q), v3 = selo(3 ^ q);
            // target = argmax of gt[t-1] (first-max semantics via strict >)
            int tg = (p1 > p0) ? 1 : 0;  float bm = fmaxf(p0, p1);
            tg = (p2 > bm) ? 2 : tg;     bm = fmaxf(p2, bm);
            tg = (p3 > bm) ? 3 : tg;
            float vtl = (tg & 1) ? v1 : v0;
            float vth = (tg & 1) ? v3 : v2;
            float vt  = (tg & 2) ? vth : vtl;
            float mx = fmaxf(fmaxf(v0, v1), fmaxf(v2, v3));
            float ss = __expf(v0 - mx) + __expf(v1 - mx) + __expf(v2 - mx) + __expf(v3 - mx);
            lloss += (mx - vt) + __logf(ss);
            // feedback class = argmax(out), first-max semantics
            int c2 = (v1 > v0) ? 1 : 0;  float bo = fmaxf(v0, v1);
            c2 = (v2 > bo) ? 2 : c2;     bo = fmaxf(v2, bo);
            c2 = (v3 > bo) ? 3 : c2;
            // gi = dec_Wih[:, c2] selected from register table
            float rl = (c2 & 1) ? Tr[1] : Tr[0], rh = (c2 & 1) ? Tr[3] : Tr[2];
            gr = (c2 & 2) ? rh : rl;
            float zl = (c2 & 1) ? Tz[1] : Tz[0], zh = (c2 & 1) ? Tz[3] : Tz[2];
            gz = (c2 & 2) ? zh : zl;
            float nl = (c2 & 1) ? Tn[1] : Tn[0], nh2 = (c2 & 1) ? Tn[3] : Tn[2];
            gn = (c2 & 2) ? nh2 : nl;
        }
        float r = fsig(ar + gr), z = fsig(az + gz);
        float n = ftanh(fmaf(r, hn, c_din + gn));
        h = fmaf(z, h - n, n);
    };

    for (int t = 0; t < S_LEN; t += 2) {
        dstep(t == 0, B0, B1, B2, B3);           // even t consumes gt[t-1] (odd index)
        int tn = t + 1;                           // always <= S-1
        B0 = gb[0 * S_LEN + tn]; B1 = gb[1 * S_LEN + tn];
        B2 = gb[2 * S_LEN + tn]; B3 = gb[3 * S_LEN + tn];
        dstep(false, A0, A1, A2, A3);             // odd t consumes gt[t-1] (even index)
        int tm = t + 2; if (tm > S_LEN - 1) tm = S_LEN - 1;
        A0 = gb[0 * S_LEN + tm]; A1 = gb[1 * S_LEN + tm];
        A2 = gb[2 * S_LEN + tm]; A3 = gb[3 * S_LEN + tm];
    }

    // ---------------- epilogue: out/nll for the final step (t = S-1) ----------------
    {
        float oa = obq;
#pragma unroll
        for (int i = 0; i < NH; ++i) {
            float hv = bperm(gbb + 4 * i, h);
            oa = fmaf(owp[i], hv, oa);
        }
        float o_b = __shfl_xor(oa, 1, 64);
        float o_c = __shfl_xor(oa, 2, 64);
        float o_d = __shfl_xor(o_b, 2, 64);
        auto selo = [&](int m) {
            float lo = (m & 1) ? o_b : oa;
            float hi = (m & 1) ? o_d : o_c;
            return (m & 2) ? hi : lo;
        };
        float v0 = selo(q), v1 = selo(1 ^ q), v2 = selo(2 ^ q), v3 = selo(3 ^ q);
        // target from gt[S-1], held in B after the final loop body
        int tg = (B1 > B0) ? 1 : 0;  float bm = fmaxf(B0, B1);
        tg = (B2 > bm) ? 2 : tg;     bm = fmaxf(B2, bm);
        tg = (B3 > bm) ? 3 : tg;
        float vtl = (tg & 1) ? v1 : v0;
        float vth = (tg & 1) ? v3 : v2;
        float vt  = (tg & 2) ? vth : vtl;
        float mx = fmaxf(fmaxf(v0, v1), fmaxf(v2, v3));
        float ss = __expf(v0 - mx) + __expf(v1 - mx) + __expf(v2 - mx) + __expf(v3 - mx);
        lloss += (mx - vt) + __logf(ss);
    }

    // ---------------- loss reduction: groups are lane-replicated; sum the 4 groups ----------------
    float ls = lloss;
    ls += __shfl_xor(ls, 16, 64);
    ls += __shfl_xor(ls, 32, 64);
    if (lane == 0) atomicAdd(loss_out, ls * (1.0f / NB));
}

extern "C" void kernel_launch(void* const* d_in, const int* in_sizes, int n_in,
                              void* d_out, int out_size, void* d_ws, size_t ws_size,
                              hipStream_t stream) {
    (void)in_sizes; (void)n_in; (void)d_ws; (void)ws_size;
    const float* gt   = (const float*)d_in[0];
    const float* eWih = (const float*)d_in[1];
    const float* eWhh = (const float*)d_in[2];
    const float* ebih = (const float*)d_in[3];
    const float* ebhh = (const float*)d_in[4];
    const float* dWih = (const float*)d_in[5];
    const float* dWhh = (const float*)d_in[6];
    const float* dbih = (const float*)d_in[7];
    const float* dbhh = (const float*)d_in[8];
    const float* oW   = (const float*)d_in[9];
    const float* ob   = (const float*)d_in[10];
    // emb (d_in[11]) is the identity; tf_rate (d_in[12]) is 1 -> argmax-feedback branch.

    float* out = (float*)d_out;
    // out[0] = loss, out[1..] = output_batch (all zeros in the tf branch).
    hipMemsetAsync(d_out, 0, (size_t)out_size * sizeof(float), stream);
    rnn_kernel<<<NB / 4, 64, 0, stream>>>(gt, eWih, eWhh, ebih, ebhh,
                                          dWih, dWhh, dbih, dbhh, oW, ob, out);
}

// Round 2
// 4014.832 us; speedup vs baseline: 1.7024x; 1.7024x over previous
//
#include <hip/hip_runtime.h>

#define S_LEN 8192
#define NH 16
#define NV 4
#define NB 512

// ---------- DPP helpers (all cross-lane traffic on the VALU pipe, no LDS) ----------
template<int R>
__device__ __forceinline__ float rotf(float v) {
    // row_ror:R within 16-lane rows (ctrl 0x120|R)
    return __int_as_float(__builtin_amdgcn_mov_dpp(__float_as_int(v), 0x120 + R, 0xF, 0xF, true));
}
__device__ __forceinline__ float qxor1(float v) {  // quad_perm [1,0,3,2] == xor 1 within quad
    return __int_as_float(__builtin_amdgcn_mov_dpp(__float_as_int(v), 0xB1, 0xF, 0xF, true));
}
__device__ __forceinline__ float qxor2(float v) {  // quad_perm [2,3,0,1] == xor 2 within quad
    return __int_as_float(__builtin_amdgcn_mov_dpp(__float_as_int(v), 0x4E, 0xF, 0xF, true));
}

template<int R>
struct RotFill {
    static __device__ __forceinline__ void run(float* hv, float h) {
        hv[R] = rotf<R>(h);
        RotFill<R + 1>::run(hv, h);
    }
};
template<>
struct RotFill<NH> {
    static __device__ __forceinline__ void run(float*, float) {}
};

__device__ __forceinline__ float fsig(float x) {
    return __builtin_amdgcn_rcpf(1.0f + __expf(-x));
}
__device__ __forceinline__ float ftanh(float x) {
    return fmaf(2.0f, __builtin_amdgcn_rcpf(1.0f + __expf(-2.0f * x)), -1.0f);
}
__device__ __forceinline__ float4 ld4(const float* p) { return *(const float4*)p; }

// 128 blocks x 64 threads. Each wave: 4 batch elements x 16 lanes.
// Lane j (within its 16-lane row) owns hidden unit j of its batch element.
__global__ __launch_bounds__(64, 1) void rnn_kernel(
    const float* __restrict__ gt,
    const float* __restrict__ eWih, const float* __restrict__ eWhh,
    const float* __restrict__ ebih, const float* __restrict__ ebhh,
    const float* __restrict__ dWih, const float* __restrict__ dWhh,
    const float* __restrict__ dbih, const float* __restrict__ dbhh,
    const float* __restrict__ oW,  const float* __restrict__ ob,
    float* __restrict__ loss_out)
{
    const int lane = threadIdx.x;          // 0..63
    const int j    = lane & 15;            // hidden index within row
    const int q    = j & 3;                // out-gate this lane accumulates
    const int b    = blockIdx.x * 4 + (lane >> 4);

    // Runtime probe of DPP row_ror direction (direction-agnostic weight indexing).
    int probe = __builtin_amdgcn_mov_dpp(j, 0x121, 0xF, 0xF, true); // row_ror:1
    const int sgn = (probe == ((j + 1) & 15)) ? 1 : -1;
    // hv[r] (== rotf<r>(h)) holds h[(j + sgn*r) & 15]

    const float* gb = gt + (size_t)b * (NV * S_LEN);   // gt[b, v, t] at gb[v*S_LEN + t]

    // ---------------- encoder weights (rotated per-lane layout) ----------------
    float ewr[NH], ewz[NH], ewn[NH];
#pragma unroll
    for (int r = 0; r < NH; ++r) {
        int k = (j + sgn * r) & 15;
        ewr[r] = eWhh[(0 * NH + j) * NH + k];
        ewz[r] = eWhh[(1 * NH + j) * NH + k];
        ewn[r] = eWhh[(2 * NH + j) * NH + k];
    }
    float exr[NV], exz[NV], exn[NV];
#pragma unroll
    for (int v = 0; v < NV; ++v) {
        exr[v] = eWih[(0 * NH + j) * NV + v];
        exz[v] = eWih[(1 * NH + j) * NV + v];
        exn[v] = eWih[(2 * NH + j) * NV + v];
    }
    const float c_er  = ebih[j] + ebhh[j];
    const float c_ez  = ebih[NH + j] + ebhh[NH + j];
    const float c_ein = ebih[2 * NH + j];
    const float c_ehn = ebhh[2 * NH + j];

    float h = 0.0f;

    auto estep = [&](float x0, float x1, float x2, float x3) {
        float hv[NH];
        hv[0] = h;
        RotFill<1>::run(hv, h);
        float ar0 = c_er, az0 = c_ez, hn0 = c_ehn;
        float ar1 = 0.f, az1 = 0.f, hn1 = 0.f;
#pragma unroll
        for (int i = 0; i < NH; i += 2) {
            ar0 = fmaf(ewr[i],     hv[i],     ar0);
            ar1 = fmaf(ewr[i + 1], hv[i + 1], ar1);
            az0 = fmaf(ewz[i],     hv[i],     az0);
            az1 = fmaf(ewz[i + 1], hv[i + 1], az1);
            hn0 = fmaf(ewn[i],     hv[i],     hn0);
            hn1 = fmaf(ewn[i + 1], hv[i + 1], hn1);
        }
        // x-dot chains are independent of h (prefetched far ahead) — scheduler fills gaps
        float xr = fmaf(exr[0], x0, fmaf(exr[1], x1, fmaf(exr[2], x2, exr[3] * x3)));
        float xz = fmaf(exz[0], x0, fmaf(exz[1], x1, fmaf(exz[2], x2, exz[3] * x3)));
        float xn = fmaf(exn[0], x0, fmaf(exn[1], x1, fmaf(exn[2], x2, exn[3] * x3)));
        float r = fsig(ar0 + ar1 + xr);
        float z = fsig(az0 + az1 + xz);
        float n = ftanh(fmaf(r, hn0 + hn1, c_ein + xn));
        h = fmaf(z, h - n, n);          // (1-z)*n + z*h
    };

    // ---------------- encoder loop: float4 x-prefetch, 8 steps/iter ----------------
    {
        float4 A0 = ld4(gb + 0 * S_LEN), A1 = ld4(gb + 1 * S_LEN),
               A2 = ld4(gb + 2 * S_LEN), A3 = ld4(gb + 3 * S_LEN);
        float4 B0 = ld4(gb + 0 * S_LEN + 4), B1 = ld4(gb + 1 * S_LEN + 4),
               B2 = ld4(gb + 2 * S_LEN + 4), B3 = ld4(gb + 3 * S_LEN + 4);
        for (int t = 0; t < S_LEN; t += 8) {
            estep(A0.x, A1.x, A2.x, A3.x);
            estep(A0.y, A1.y, A2.y, A3.y);
            estep(A0.z, A1.z, A2.z, A3.z);
            estep(A0.w, A1.w, A2.w, A3.w);
            int ta = t + 8;  if (ta > S_LEN - 4) ta = S_LEN - 4;
            A0 = ld4(gb + 0 * S_LEN + ta); A1 = ld4(gb + 1 * S_LEN + ta);
            A2 = ld4(gb + 2 * S_LEN + ta); A3 = ld4(gb + 3 * S_LEN + ta);
            estep(B0.x, B1.x, B2.x, B3.x);
            estep(B0.y, B1.y, B2.y, B3.y);
            estep(B0.z, B1.z, B2.z, B3.z);
            estep(B0.w, B1.w, B2.w, B3.w);
            int tb = t + 12; if (tb > S_LEN - 4) tb = S_LEN - 4;
            B0 = ld4(gb + 0 * S_LEN + tb); B1 = ld4(gb + 1 * S_LEN + tb);
            B2 = ld4(gb + 2 * S_LEN + tb); B3 = ld4(gb + 3 * S_LEN + tb);
        }
    }

    // ---------------- decoder weights ----------------
    float dwr[NH], dwz[NH], dwn[NH], owp[NH];
#pragma unroll
    for (int r = 0; r < NH; ++r) {
        int k = (j + sgn * r) & 15;
        dwr[r] = dWhh[(0 * NH + j) * NH + k];
        dwz[r] = dWhh[(1 * NH + j) * NH + k];
        dwn[r] = dWhh[(2 * NH + j) * NH + k];
        owp[r] = oW[q * NH + k];
    }
    float Tr[NV], Tz[NV], Tn[NV];
#pragma unroll
    for (int c = 0; c < NV; ++c) {
        Tr[c] = dWih[(0 * NH + j) * NV + c];
        Tz[c] = dWih[(1 * NH + j) * NV + c];
        Tn[c] = dWih[(2 * NH + j) * NV + c];
    }
    const float c_dr  = dbih[j] + dbhh[j];
    const float c_dz  = dbih[NH + j] + dbhh[NH + j];
    const float c_din = dbih[2 * NH + j];
    const float c_dhn = dbhh[2 * NH + j];
    const float obq   = ob[q];

    float lloss = 0.0f;

    // dstep at time t: gathers h'(t-1), accumulates GRU dots + output head of step t-1,
    // finishes nll/argmax for t-1 (targets p0..p3 = gt[t-1]), selects one-hot gi, updates h.
    auto dstep = [&](bool first, float p0, float p1, float p2, float p3) {
        float hv[NH];
        hv[0] = h;
        RotFill<1>::run(hv, h);
        float ar0 = c_dr, az0 = c_dz, hn0 = c_dhn, oa0 = obq;
        float ar1 = 0.f, az1 = 0.f, hn1 = 0.f, oa1 = 0.f;
#pragma unroll
        for (int i = 0; i < NH; i += 2) {
            ar0 = fmaf(dwr[i],     hv[i],     ar0);
            ar1 = fmaf(dwr[i + 1], hv[i + 1], ar1);
            az0 = fmaf(dwz[i],     hv[i],     az0);
            az1 = fmaf(dwz[i + 1], hv[i + 1], az1);
            hn0 = fmaf(dwn[i],     hv[i],     hn0);
            hn1 = fmaf(dwn[i + 1], hv[i + 1], hn1);
            oa0 = fmaf(owp[i],     hv[i],     oa0);
            oa1 = fmaf(owp[i + 1], hv[i + 1], oa1);
        }
        float gr, gz, gn;
        if (first) {
            gr = gz = gn = 0.0f;             // x0 = zeros
        } else {
            float oa  = oa0 + oa1;
            float o_b = qxor1(oa);           // out[q^1]
            float o_c = qxor2(oa);           // out[q^2]
            float o_d = qxor2(o_b);          // out[q^3]
            auto selo = [&](int m) {         // out[i] lives in register m = i ^ q
                float lo = (m & 1) ? o_b : oa;
                float hi = (m & 1) ? o_d : o_c;
                return (m & 2) ? hi : lo;
            };
            float v0 = selo(q), v1 = selo(1 ^ q), v2 = selo(2 ^ q), v3 = selo(3 ^ q);
            // target = argmax of gt[t-1] (first-max semantics)
            int tg = (p1 > p0) ? 1 : 0;  float bm = fmaxf(p0, p1);
            tg = (p2 > bm) ? 2 : tg;     bm = fmaxf(p2, bm);
            tg = (p3 > bm) ? 3 : tg;
            float vtl = (tg & 1) ? v1 : v0;
            float vth = (tg & 1) ? v3 : v2;
            float vt  = (tg & 2) ? vth : vtl;
            float mx = fmaxf(fmaxf(v0, v1), fmaxf(v2, v3));
            float ss = __expf(v0 - mx) + __expf(v1 - mx) + __expf(v2 - mx) + __expf(v3 - mx);
            lloss += (mx - vt) + __logf(ss);
            // feedback class = argmax(out)
            int c2 = (v1 > v0) ? 1 : 0;  float bo = fmaxf(v0, v1);
            c2 = (v2 > bo) ? 2 : c2;     bo = fmaxf(v2, bo);
            c2 = (v3 > bo) ? 3 : c2;
            float rl = (c2 & 1) ? Tr[1] : Tr[0], rh = (c2 & 1) ? Tr[3] : Tr[2];
            gr = (c2 & 2) ? rh : rl;
            float zl = (c2 & 1) ? Tz[1] : Tz[0], zh = (c2 & 1) ? Tz[3] : Tz[2];
            gz = (c2 & 2) ? zh : zl;
            float nl = (c2 & 1) ? Tn[1] : Tn[0], nh2 = (c2 & 1) ? Tn[3] : Tn[2];
            gn = (c2 & 2) ? nh2 : nl;
        }
        float r = fsig(ar0 + ar1 + gr);
        float z = fsig(az0 + az1 + gz);
        float n = ftanh(fmaf(r, hn0 + hn1, c_din + gn));
        h = fmaf(z, h - n, n);
    };

    // ---------------- decoder loop ----------------
    float lastw0, lastw1, lastw2, lastw3;   // gt[S-1] targets for the epilogue
    {
        dstep(true, 0.f, 0.f, 0.f, 0.f);    // t = 0, x0 = zeros
        float4 A0 = ld4(gb + 0 * S_LEN), A1 = ld4(gb + 1 * S_LEN),
               A2 = ld4(gb + 2 * S_LEN), A3 = ld4(gb + 3 * S_LEN);     // u = 0..3
        float4 B0 = ld4(gb + 0 * S_LEN + 4), B1 = ld4(gb + 1 * S_LEN + 4),
               B2 = ld4(gb + 2 * S_LEN + 4), B3 = ld4(gb + 3 * S_LEN + 4); // u = 4..7
        for (int u = 0; u < S_LEN - 8; u += 8) {
            dstep(false, A0.x, A1.x, A2.x, A3.x);
            dstep(false, A0.y, A1.y, A2.y, A3.y);
            dstep(false, A0.z, A1.z, A2.z, A3.z);
            dstep(false, A0.w, A1.w, A2.w, A3.w);
            A0 = ld4(gb + 0 * S_LEN + u + 8);  A1 = ld4(gb + 1 * S_LEN + u + 8);
            A2 = ld4(gb + 2 * S_LEN + u + 8);  A3 = ld4(gb + 3 * S_LEN + u + 8);
            dstep(false, B0.x, B1.x, B2.x, B3.x);
            dstep(false, B0.y, B1.y, B2.y, B3.y);
            dstep(false, B0.z, B1.z, B2.z, B3.z);
            dstep(false, B0.w, B1.w, B2.w, B3.w);
            B0 = ld4(gb + 0 * S_LEN + u + 12); B1 = ld4(gb + 1 * S_LEN + u + 12);
            B2 = ld4(gb + 2 * S_LEN + u + 12); B3 = ld4(gb + 3 * S_LEN + u + 12);
        }
        // A = gt[S-8..S-5], B = gt[S-4..S-1]
        dstep(false, A0.x, A1.x, A2.x, A3.x);
        dstep(false, A0.y, A1.y, A2.y, A3.y);
        dstep(false, A0.z, A1.z, A2.z, A3.z);
        dstep(false, A0.w, A1.w, A2.w, A3.w);
        dstep(false, B0.x, B1.x, B2.x, B3.x);
        dstep(false, B0.y, B1.y, B2.y, B3.y);
        dstep(false, B0.z, B1.z, B2.z, B3.z);
        lastw0 = B0.w; lastw1 = B1.w; lastw2 = B2.w; lastw3 = B3.w;
    }

    // ---------------- epilogue: out/nll for the final step (t = S-1) ----------------
    {
        float hv[NH];
        hv[0] = h;
        RotFill<1>::run(hv, h);
        float oa0 = obq, oa1 = 0.f;
#pragma unroll
        for (int i = 0; i < NH; i += 2) {
            oa0 = fmaf(owp[i],     hv[i],     oa0);
            oa1 = fmaf(owp[i + 1], hv[i + 1], oa1);
        }
        float oa  = oa0 + oa1;
        float o_b = qxor1(oa);
        float o_c = qxor2(oa);
        float o_d = qxor2(o_b);
        auto selo = [&](int m) {
            float lo = (m & 1) ? o_b : oa;
            float hi = (m & 1) ? o_d : o_c;
            return (m & 2) ? hi : lo;
        };
        float v0 = selo(q), v1 = selo(1 ^ q), v2 = selo(2 ^ q), v3 = selo(3 ^ q);
        int tg = (lastw1 > lastw0) ? 1 : 0;  float bm = fmaxf(lastw0, lastw1);
        tg = (lastw2 > bm) ? 2 : tg;         bm = fmaxf(lastw2, bm);
        tg = (lastw3 > bm) ? 3 : tg;
        float vtl = (tg & 1) ? v1 : v0;
        float vth = (tg & 1) ? v3 : v2;
        float vt  = (tg & 2) ? vth : vtl;
        float mx = fmaxf(fmaxf(v0, v1), fmaxf(v2, v3));
        float ss = __expf(v0 - mx) + __expf(v1 - mx) + __expf(v2 - mx) + __expf(v3 - mx);
        lloss += (mx - vt) + __logf(ss);
    }

    // ---------------- loss reduction: 16-lane rows are replicated; sum the 4 rows ----------------
    float ls = lloss;
    ls += __shfl_xor(ls, 16, 64);
    ls += __shfl_xor(ls, 32, 64);
    if (lane == 0) atomicAdd(loss_out, ls * (1.0f / NB));
}

extern "C" void kernel_launch(void* const* d_in, const int* in_sizes, int n_in,
                              void* d_out, int out_size, void* d_ws, size_t ws_size,
                              hipStream_t stream) {
    (void)in_sizes; (void)n_in; (void)d_ws; (void)ws_size;
    const float* gt   = (const float*)d_in[0];
    const float* eWih = (const float*)d_in[1];
    const float* eWhh = (const float*)d_in[2];
    const float* ebih = (const float*)d_in[3];
    const float* ebhh = (const float*)d_in[4];
    const float* dWih = (const float*)d_in[5];
    const float* dWhh = (const float*)d_in[6];
    const float* dbih = (const float*)d_in[7];
    const float* dbhh = (const float*)d_in[8];
    const float* oW   = (const float*)d_in[9];
    const float* ob   = (const float*)d_in[10];
    // emb (d_in[11]) is identity; tf_rate (d_in[12]) == 1 -> argmax-feedback branch.

    float* out = (float*)d_out;
    // out[0] = loss, out[1..] = output_batch (all zeros in the tf branch).
    hipMemsetAsync(d_out, 0, (size_t)out_size * sizeof(float), stream);
    rnn_kernel<<<NB / 4, 64, 0, stream>>>(gt, eWih, eWhh, ebih, ebhh,
                                          dWih, dWhh, dbih, dbhh, oW, ob, out);
}